// Round 5
// baseline (652.655 us; speedup 1.0000x reference)
//
#include <hip/hip_runtime.h>
#include <hip/hip_bf16.h>

typedef short bf16x8 __attribute__((ext_vector_type(8)));
typedef float f32x4 __attribute__((ext_vector_type(4)));
typedef _Float16 h2f __attribute__((ext_vector_type(2)));

#define DEVINL static __device__ __forceinline__

DEVINL float bf2f(ushort u) {
    union { unsigned int i; float f; } v;
    v.i = ((unsigned int)u) << 16;
    return v.f;
}
DEVINL ushort f2bf(float f) {
    union { float f; unsigned int i; } v;
    v.f = f;
    unsigned int r = v.i + 0x7FFFu + ((v.i >> 16) & 1u);
    return (ushort)(r >> 16);
}
DEVINL float sigmoid_f(float x) {
    x = fminf(fmaxf(x, -30.f), 30.f);
    return 1.f / (1.f + __expf(-x));
}
DEVINL float tanh_f(float x) {
    x = fminf(fmaxf(x, -15.f), 15.f);
    float e = __expf(-2.f * x);
    return (1.f - e) / (1.f + e);
}
DEVINL h2f as_h2(unsigned int u) {
    union { unsigned int u; h2f h; } v;
    v.u = u;
    return v.h;
}
DEVINL float hdot(h2f a, h2f b, float c) {
#if __has_builtin(__builtin_amdgcn_fdot2)
    return __builtin_amdgcn_fdot2(a, b, c, false);
#else
    h2f p = a * b;
    return c + (float)p[0] + (float)p[1];
#endif
}

#define TT 16

// ---------------------------------------------------------------------------
// Stage A: pw1(MFMA) + LN1 + PReLU + dw3x3 + BN + PReLU + pw2(MFMA) + LN2
//          -> h2 (f32, into d_out even channels) + zt [b][t][32] f32
// grid: 256 blocks (b * 32 t-chunks), 512 threads (8 waves)
// wave wv owns f-columns [16*wv, 16*wv+16) for ALL channel rows -> LN wave-local
// ---------------------------------------------------------------------------
__global__ __launch_bounds__(512, 2) void stageA_kernel(
    const float* __restrict__ x, const float* __restrict__ pw1w,
    const float* __restrict__ pw1b, const float* __restrict__ ln1g,
    const float* __restrict__ ln1b, const float* __restrict__ pr1,
    const float* __restrict__ dww, const float* __restrict__ dwb_,
    const float* __restrict__ bng, const float* __restrict__ bnb,
    const float* __restrict__ bnm, const float* __restrict__ bnv,
    const float* __restrict__ pr2, const float* __restrict__ pw2w,
    const float* __restrict__ pw2b, const float* __restrict__ ln2g,
    const float* __restrict__ ln2b,
    float* __restrict__ outp, float* __restrict__ ztout)
{
    // x1T[fp][ch]: fp = f+1 (rows 0 and 129 zero f-padding), pitch 40
    __shared__ __align__(16) ushort x1T[130][40];
    // ring of LN1+PReLU output, bf16, col = f+2 (cols 0,1,130,131 zero)
    __shared__ __align__(16) ushort ring[3][64][132];
    // transposed dw output for pw2 B-fragments: [f][o]
    __shared__ __align__(16) ushort HdT[128][72];
    __shared__ float ztp[8][32];

    const int tid = threadIdx.x;
    const int lane = tid & 63;
    const int wv = tid >> 6;     // 0..7 : f-tile
    const int lg = lane >> 4;    // 0..3 : k-group / row-group
    const int lr = lane & 15;    // 0..15: col within tile / row within A
    const int b = blockIdx.x >> 5;
    const int t0 = (blockIdx.x & 31) * TT;
    const int fcol = 16 * wv + lr;

    // ---- preload pw1 A-fragments: A[row=lr][k=8*lg+j] = W_kk[16*ot+lr][ch] ----
    bf16x8 a1f[4][3];
    #pragma unroll
    for (int ot = 0; ot < 4; ++ot)
        #pragma unroll
        for (int kk = 0; kk < 3; ++kk)
            #pragma unroll
            for (int j = 0; j < 8; ++j)
                a1f[ot][kk][j] = (short)f2bf(pw1w[(16 * ot + lr) * 96 + 3 * (8 * lg + j) + kk]);

    float b1v[16], g1v[16], be1v[16];
    #pragma unroll
    for (int ot = 0; ot < 4; ++ot)
        #pragma unroll
        for (int jj = 0; jj < 4; ++jj) {
            int o = 16 * ot + 4 * lg + jj;
            b1v[ot * 4 + jj] = pw1b[o];
            g1v[ot * 4 + jj] = ln1g[o];
            be1v[ot * 4 + jj] = ln1b[o];
        }
    const float alpha1 = pr1[0];
    const float alpha2 = pr2[0];

    // depthwise params, lane-indexed (o = lane)
    float wd[9];
    #pragma unroll
    for (int i = 0; i < 9; ++i) wd[i] = dww[lane * 9 + i];
    const float dwbias = dwb_[lane];
    const float bninv = bng[lane] * rsqrtf(bnv[lane] + 1e-5f);
    const float bnsh = bnb[lane] - bnm[lane] * bninv;

    // pw2 A-fragments
    bf16x8 a2f[2][2];
    #pragma unroll
    for (int ot = 0; ot < 2; ++ot)
        #pragma unroll
        for (int ks = 0; ks < 2; ++ks)
            #pragma unroll
            for (int j = 0; j < 8; ++j)
                a2f[ot][ks][j] = (short)f2bf(pw2w[(16 * ot + lr) * 64 + 32 * ks + 8 * lg + j]);

    float b2v[8], g2v[8], be2v[8];
    #pragma unroll
    for (int ot = 0; ot < 2; ++ot)
        #pragma unroll
        for (int jj = 0; jj < 4; ++jj) {
            int o = 16 * ot + 4 * lg + jj;
            b2v[ot * 4 + jj] = pw2b[o];
            g2v[ot * 4 + jj] = ln2g[o];
            be2v[ot * 4 + jj] = ln2b[o];
        }

    // zero ring f-borders once (never touched by compute writes)
    for (int i = tid; i < 3 * 64; i += 512) {
        int sl = i >> 6, o = i & 63;
        ring[sl][o][0] = 0; ring[sl][o][1] = 0;
        ring[sl][o][130] = 0; ring[sl][o][131] = 0;
    }

    for (int s = 0; s < TT + 2; ++s) {
        const int tt = t0 - 2 + s;
        __syncthreads();
        // ---- stage x slice (f32 -> bf16, transposed) ----
        if (tt >= 0) {
            const int ch = tid >> 4, f0 = (tid & 15) << 3;
            const float* xp = x + (((size_t)(b * 64 + ch) * 512 + tt) * 128 + f0);
            float4 v0 = *(const float4*)xp;
            float4 v1 = *(const float4*)(xp + 4);
            x1T[f0 + 1][ch] = f2bf(v0.x); x1T[f0 + 2][ch] = f2bf(v0.y);
            x1T[f0 + 3][ch] = f2bf(v0.z); x1T[f0 + 4][ch] = f2bf(v0.w);
            x1T[f0 + 5][ch] = f2bf(v1.x); x1T[f0 + 6][ch] = f2bf(v1.y);
            x1T[f0 + 7][ch] = f2bf(v1.z); x1T[f0 + 8][ch] = f2bf(v1.w);
            if (tid < 40) { x1T[0][tid] = 0; x1T[129][tid] = 0; }
        }
        __syncthreads();
        const int slot = s % 3;
        if (tt >= 0) {
            // ---- pw1 MFMA: H(64x128) = sum_kk Wkk(64x32) @ Xkk(32x128) ----
            f32x4 acc[4] = {};
            #pragma unroll
            for (int kk = 0; kk < 3; ++kk) {
                bf16x8 bfr = *(const bf16x8*)&x1T[16 * wv + lr + kk][8 * lg];
                #pragma unroll
                for (int ot = 0; ot < 4; ++ot)
                    acc[ot] = __builtin_amdgcn_mfma_f32_16x16x32_bf16(a1f[ot][kk], bfr, acc[ot], 0, 0, 0);
            }
            // ---- LN1 over 64 channels (wave-local: reduce over lane-groups) ----
            float vals[16];
            float sm = 0.f, sq = 0.f;
            #pragma unroll
            for (int ot = 0; ot < 4; ++ot)
                #pragma unroll
                for (int jj = 0; jj < 4; ++jj) {
                    float v2 = acc[ot][jj] + b1v[ot * 4 + jj];
                    vals[ot * 4 + jj] = v2; sm += v2; sq += v2 * v2;
                }
            sm += __shfl_xor(sm, 16); sm += __shfl_xor(sm, 32);
            sq += __shfl_xor(sq, 16); sq += __shfl_xor(sq, 32);
            const float mu = sm * (1.f / 64.f);
            const float rs = rsqrtf(sq * (1.f / 64.f) - mu * mu + 1e-6f);
            #pragma unroll
            for (int ot = 0; ot < 4; ++ot)
                #pragma unroll
                for (int jj = 0; jj < 4; ++jj) {
                    float y = (vals[ot * 4 + jj] - mu) * rs * g1v[ot * 4 + jj] + be1v[ot * 4 + jj];
                    y = (y >= 0.f) ? y : alpha1 * y;
                    ring[slot][16 * ot + 4 * lg + jj][2 + fcol] = f2bf(y);
                }
        } else {
            // causal T-padding: zero slot
            for (int i = tid; i < 64 * 132; i += 512)
                ((ushort*)ring[slot])[i] = 0;
        }
        if (s >= 2) {
            const int tau = tt;
            __syncthreads();
            // ---- depthwise 3x3 (+bias+BN+PReLU): lane = o, wave = f-block ----
            float hd[16] = {};
            #pragma unroll
            for (int kt = 0; kt < 3; ++kt) {
                const int slk = (s - 2 + kt) % 3;
                float rowv[20];
                #pragma unroll
                for (int i = 0; i < 5; ++i) {
                    uint2 q = *(const uint2*)&ring[slk][lane][16 * wv + 4 * i];
                    const ushort* p = (const ushort*)&q;
                    rowv[4 * i + 0] = bf2f(p[0]); rowv[4 * i + 1] = bf2f(p[1]);
                    rowv[4 * i + 2] = bf2f(p[2]); rowv[4 * i + 3] = bf2f(p[3]);
                }
                #pragma unroll
                for (int fo = 0; fo < 16; ++fo)
                    hd[fo] += wd[kt * 3 + 0] * rowv[fo + 1] + wd[kt * 3 + 1] * rowv[fo + 2]
                            + wd[kt * 3 + 2] * rowv[fo + 3];
            }
            #pragma unroll
            for (int fo = 0; fo < 16; ++fo) {
                float v2 = hd[fo] + dwbias;
                v2 = v2 * bninv + bnsh;
                v2 = (v2 >= 0.f) ? v2 : alpha2 * v2;
                HdT[16 * wv + fo][lane] = f2bf(v2);
            }
            __syncthreads();
            // ---- pw2 MFMA: G(32x128) = W2(32x64) @ Hd(64x128) ----
            f32x4 acc2[2] = {};
            #pragma unroll
            for (int ks = 0; ks < 2; ++ks) {
                bf16x8 bfr = *(const bf16x8*)&HdT[16 * wv + lr][32 * ks + 8 * lg];
                #pragma unroll
                for (int ot = 0; ot < 2; ++ot)
                    acc2[ot] = __builtin_amdgcn_mfma_f32_16x16x32_bf16(a2f[ot][ks], bfr, acc2[ot], 0, 0, 0);
            }
            // ---- LN2 over 32 channels (wave-local) ----
            float vals2[8];
            float sm2 = 0.f, sq2 = 0.f;
            #pragma unroll
            for (int ot = 0; ot < 2; ++ot)
                #pragma unroll
                for (int jj = 0; jj < 4; ++jj) {
                    float v2 = acc2[ot][jj] + b2v[ot * 4 + jj];
                    vals2[ot * 4 + jj] = v2; sm2 += v2; sq2 += v2 * v2;
                }
            sm2 += __shfl_xor(sm2, 16); sm2 += __shfl_xor(sm2, 32);
            sq2 += __shfl_xor(sq2, 16); sq2 += __shfl_xor(sq2, 32);
            const float mu2 = sm2 * (1.f / 32.f);
            const float rs2 = rsqrtf(sq2 * (1.f / 32.f) - mu2 * mu2 + 1e-6f);
            float zpart[8];
            #pragma unroll
            for (int ot = 0; ot < 2; ++ot)
                #pragma unroll
                for (int jj = 0; jj < 4; ++jj) {
                    float y = (vals2[ot * 4 + jj] - mu2) * rs2 * g2v[ot * 4 + jj] + be2v[ot * 4 + jj];
                    const int o = 16 * ot + 4 * lg + jj;
                    // h2 (f32) -> even output channel 2*o (gated later in place)
                    outp[(((size_t)(b * 64 + 2 * o) * 512 + tau) * 128) + fcol] = y;
                    zpart[ot * 4 + jj] = y * y;
                }
            // zt partial: reduce over f within lane-group (lr lanes)
            #pragma unroll
            for (int k = 0; k < 8; ++k) {
                float v2 = zpart[k];
                v2 += __shfl_xor(v2, 1); v2 += __shfl_xor(v2, 2);
                v2 += __shfl_xor(v2, 4); v2 += __shfl_xor(v2, 8);
                zpart[k] = v2;
            }
            if (lr == 0) {
                #pragma unroll
                for (int ot = 0; ot < 2; ++ot)
                    #pragma unroll
                    for (int jj = 0; jj < 4; ++jj)
                        ztp[wv][16 * ot + 4 * lg + jj] = zpart[ot * 4 + jj];
            }
            __syncthreads();
            if (tid < 32) {
                float a = 0.f;
                #pragma unroll
                for (int w = 0; w < 8; ++w) a += ztp[w][tid];
                ztout[((size_t)b * 512 + tau) * 32 + tid] = a * (1.f / 128.f);
            }
        }
    }
}

// ---------------------------------------------------------------------------
// xg[b][t][g] = bih[g] + sum_c wih[g][c] * zt[b][t][c]
// ---------------------------------------------------------------------------
__global__ __launch_bounds__(256) void xg_kernel(
    const float* __restrict__ zt, const float* __restrict__ wih,
    const float* __restrict__ bih, float* __restrict__ xg)
{
    const int idx = blockIdx.x * 256 + threadIdx.x;
    const int g = idx % 192;
    const int bt = idx / 192;
    if (bt >= 4096) return;
    const float* z = zt + (size_t)bt * 32;
    float acc = bih[g];
    #pragma unroll 8
    for (int c = 0; c < 32; ++c) acc += wih[g * 32 + c] * z[c];
    xg[(size_t)bt * 192 + g] = acc;
}

// ---------------------------------------------------------------------------
// GRU scan: one wave per batch element. Lane c owns whh rows {c,64+c,128+c}
// as f16x2 in registers; h redistributed via LDS each step.
// ---------------------------------------------------------------------------
__global__ __launch_bounds__(64) void gru_kernel(
    const float* __restrict__ xg, const float* __restrict__ whh,
    const float* __restrict__ bhh, float* __restrict__ hs)
{
    const int b = blockIdx.x;
    const int c = threadIdx.x;
    __shared__ __align__(16) _Float16 hbuf[2][64];
    h2f w0[32], w1[32], w2[32];
    #pragma unroll
    for (int i = 0; i < 32; ++i) {
        w0[i][0] = (_Float16)whh[c * 64 + 2 * i];
        w0[i][1] = (_Float16)whh[c * 64 + 2 * i + 1];
        w1[i][0] = (_Float16)whh[(64 + c) * 64 + 2 * i];
        w1[i][1] = (_Float16)whh[(64 + c) * 64 + 2 * i + 1];
        w2[i][0] = (_Float16)whh[(128 + c) * 64 + 2 * i];
        w2[i][1] = (_Float16)whh[(128 + c) * 64 + 2 * i + 1];
    }
    const float bh0 = bhh[c];
    const float bh1 = bhh[64 + c];
    const float bh2 = bhh[128 + c];
    h2f hv[32];
    #pragma unroll
    for (int i = 0; i < 32; ++i) { hv[i][0] = (_Float16)0.f; hv[i][1] = (_Float16)0.f; }
    float hmy = 0.f;
    const float* xgb = xg + (size_t)b * 512 * 192;
    float* hsb = hs + (size_t)b * 512 * 64;
    float xr = xgb[c], xz = xgb[64 + c], xn = xgb[128 + c];
    for (int t = 0; t < 512; ++t) {
        float nxr = 0.f, nxz = 0.f, nxn = 0.f;
        if (t < 511) {
            const float* p = xgb + (size_t)(t + 1) * 192;
            nxr = p[c]; nxz = p[64 + c]; nxn = p[128 + c];
        }
        float a0 = bh0, a1 = 0.f, a2 = bh1, a3 = 0.f, a4 = bh2, a5 = 0.f;
        #pragma unroll
        for (int i = 0; i < 32; i += 2) {
            a0 = hdot(w0[i], hv[i], a0); a1 = hdot(w0[i + 1], hv[i + 1], a1);
            a2 = hdot(w1[i], hv[i], a2); a3 = hdot(w1[i + 1], hv[i + 1], a3);
            a4 = hdot(w2[i], hv[i], a4); a5 = hdot(w2[i + 1], hv[i + 1], a5);
        }
        const float r = sigmoid_f(xr + a0 + a1);
        const float z = sigmoid_f(xz + a2 + a3);
        const float n = tanh_f(xn + r * (a4 + a5));
        const float hn = (1.f - z) * n + z * hmy;
        hmy = hn;
        hsb[(size_t)t * 64 + c] = hn;
        const int bi = t & 1;
        hbuf[bi][c] = (_Float16)hn;
        __syncthreads();
        const uint4* q4 = (const uint4*)hbuf[bi];
        #pragma unroll
        for (int i = 0; i < 8; ++i) {
            uint4 q = q4[i];
            hv[4 * i + 0] = as_h2(q.x); hv[4 * i + 1] = as_h2(q.y);
            hv[4 * i + 2] = as_h2(q.z); hv[4 * i + 3] = as_h2(q.w);
        }
        xr = nxr; xz = nxz; xn = nxn;
    }
}

// ---------------------------------------------------------------------------
// Stage C (f32 I/O): at = sigmoid(fc(hs)); gate even channels of out in place;
// copy x2 into odd channels. grid: 8 b * 64 t-chunks, 256 threads.
// ---------------------------------------------------------------------------
__global__ __launch_bounds__(256) void stageC_kernel(
    const float* __restrict__ hs, const float* __restrict__ fcw,
    const float* __restrict__ fcb, const float* __restrict__ x,
    float* __restrict__ outp)
{
    __shared__ float fw[32][66];
    __shared__ float hsl[8][64];
    __shared__ float atl[8][32];
    const int tid = threadIdx.x;
    const int b = blockIdx.x >> 6;
    const int t0 = (blockIdx.x & 63) * 8;
    for (int i = tid; i < 2048; i += 256) fw[i >> 6][i & 63] = fcw[i];
    for (int i = tid; i < 512; i += 256) hsl[i >> 6][i & 63] = hs[((size_t)b * 512 + t0) * 64 + i];
    __syncthreads();
    {
        const int t = tid >> 5, o = tid & 31;
        float acc = fcb[o];
        #pragma unroll 8
        for (int g = 0; g < 64; ++g) acc += fw[o][g] * hsl[t][g];
        atl[t][o] = sigmoid_f(acc);
    }
    __syncthreads();
    // 8t * 64c * 128f = 65536 f32 per block; 256 thr * 32 iters * 8 f32
    #pragma unroll
    for (int k = 0; k < 32; ++k) {
        const int i = tid + (k << 8);
        const int f0 = (i & 15) << 3;
        const int c = (i >> 4) & 63;
        const int tl = i >> 10;
        const int t = t0 + tl;
        const int ch = c >> 1;
        float* op = outp + ((size_t)(b * 64 + c) * 512 + t) * 128 + f0;
        if (c & 1) {
            const float* xp = x + (((size_t)(b * 64 + 32 + ch) * 512 + t) * 128 + f0);
            float4 v0 = *(const float4*)xp;
            float4 v1 = *(const float4*)(xp + 4);
            *(float4*)op = v0;
            *(float4*)(op + 4) = v1;
        } else {
            const float a = atl[tl][ch];
            float4 v0 = *(const float4*)op;
            float4 v1 = *(const float4*)(op + 4);
            v0.x *= a; v0.y *= a; v0.z *= a; v0.w *= a;
            v1.x *= a; v1.y *= a; v1.z *= a; v1.w *= a;
            *(float4*)op = v0;
            *(float4*)(op + 4) = v1;
        }
    }
}

extern "C" void kernel_launch(void* const* d_in, const int* in_sizes, int n_in,
                              void* d_out, int out_size, void* d_ws, size_t ws_size,
                              hipStream_t stream) {
    (void)in_sizes; (void)n_in; (void)out_size; (void)ws_size;
    const float* x    = (const float*)d_in[0];
    const float* pw1w = (const float*)d_in[1];
    const float* pw1b = (const float*)d_in[2];
    const float* ln1g = (const float*)d_in[3];
    const float* ln1b = (const float*)d_in[4];
    const float* pr1  = (const float*)d_in[5];
    const float* dww  = (const float*)d_in[6];
    const float* dwb  = (const float*)d_in[7];
    const float* bng  = (const float*)d_in[8];
    const float* bnb  = (const float*)d_in[9];
    const float* bnm  = (const float*)d_in[10];
    const float* bnv  = (const float*)d_in[11];
    const float* pr2  = (const float*)d_in[12];
    const float* pw2w = (const float*)d_in[13];
    const float* pw2b = (const float*)d_in[14];
    const float* ln2g = (const float*)d_in[15];
    const float* ln2b = (const float*)d_in[16];
    const float* wih  = (const float*)d_in[17];
    const float* whh  = (const float*)d_in[18];
    const float* bih  = (const float*)d_in[19];
    const float* bhh  = (const float*)d_in[20];
    const float* fcw  = (const float*)d_in[21];
    const float* fcb  = (const float*)d_in[22];
    float* outp = (float*)d_out;
    char* ws = (char*)d_ws;
    float* ztbuf = (float*)ws;                      // 8*512*32  f32 =   524,288 B
    float* xgbuf = (float*)(ws + 524288);           // 8*512*192 f32 = 3,145,728 B
    float* hsbuf = (float*)(ws + 524288 + 3145728); // 8*512*64  f32 = 1,048,576 B

    stageA_kernel<<<256, 512, 0, stream>>>(x, pw1w, pw1b, ln1g, ln1b, pr1, dww, dwb,
                                           bng, bnb, bnm, bnv, pr2, pw2w, pw2b, ln2g, ln2b,
                                           outp, ztbuf);
    xg_kernel<<<3072, 256, 0, stream>>>(ztbuf, wih, bih, xgbuf);
    gru_kernel<<<8, 64, 0, stream>>>(xgbuf, whh, bhh, hsbuf);
    stageC_kernel<<<512, 256, 0, stream>>>(hsbuf, fcw, fcb, x, outp);
}